// Round 1
// baseline (1133.745 us; speedup 1.0000x reference)
//
#include <hip/hip_runtime.h>
#include <hip/hip_bf16.h>
#include <math.h>

#define H 64
#define H2 128
#define EPS_MSG 1e-7f
#define LN_EPS 1e-5f

__device__ __forceinline__ float wave_sum(float v) {
    #pragma unroll
    for (int o = 32; o > 0; o >>= 1) v += __shfl_xor(v, o, 64);
    return v;
}

// ---------------- CSR build ----------------
__global__ void hist_k(const int* __restrict__ dst, int* __restrict__ counts, int E) {
    int e = blockIdx.x * blockDim.x + threadIdx.x;
    if (e < E) atomicAdd(&counts[dst[e]], 1);
}

__global__ void scan_block_k(const int* __restrict__ counts, int* __restrict__ partial,
                             int* __restrict__ blockSums, int n) {
    __shared__ int tmp[256];
    int tid = threadIdx.x;
    int i = blockIdx.x * 256 + tid;
    tmp[tid] = (i < n) ? counts[i] : 0;
    __syncthreads();
    #pragma unroll
    for (int off = 1; off < 256; off <<= 1) {
        int t = (tid >= off) ? tmp[tid - off] : 0;
        __syncthreads();
        tmp[tid] += t;
        __syncthreads();
    }
    if (i < n) partial[i] = tmp[tid];
    if (tid == 255) blockSums[blockIdx.x] = tmp[255];
}

__global__ void scan_sums_k(int* __restrict__ blockSums, int nb) {
    __shared__ int tmp[512];
    int tid = threadIdx.x;
    tmp[tid] = (tid < nb) ? blockSums[tid] : 0;
    __syncthreads();
    #pragma unroll
    for (int off = 1; off < 512; off <<= 1) {
        int t = (tid >= off) ? tmp[tid - off] : 0;
        __syncthreads();
        tmp[tid] += t;
        __syncthreads();
    }
    if (tid < nb) blockSums[tid] = (tid == 0) ? 0 : tmp[tid - 1];  // exclusive
}

__global__ void finalize_k(const int* __restrict__ partial, const int* __restrict__ blockSums,
                           const int* __restrict__ counts, int* __restrict__ row_start,
                           int* __restrict__ cursor, int n) {
    int i = blockIdx.x * blockDim.x + threadIdx.x;
    if (i < n) {
        int rs = partial[i] + blockSums[i >> 8];   // inclusive prefix
        row_start[i + 1] = rs;
        cursor[i] = rs - counts[i];                // exclusive prefix
        if (i == 0) row_start[0] = 0;
    }
}

__global__ void scatter_k(const int* __restrict__ src, const int* __restrict__ dst,
                          int* __restrict__ cursor, int* __restrict__ srcs_sorted, int E) {
    int e = blockIdx.x * blockDim.x + threadIdx.x;
    if (e < E) {
        int d = dst[e];
        int pos = atomicAdd(&cursor[d], 1);
        srcs_sorted[pos] = src[e];
    }
}

// ---------------- encoder: A = x @ enc_W + enc_b ----------------
__global__ void encoder_k(const float* __restrict__ x, const float* __restrict__ W,
                          const float* __restrict__ b, float* __restrict__ A, int Nn) {
    int idx = blockIdx.x * blockDim.x + threadIdx.x;
    if (idx >= Nn * H) return;
    int n = idx >> 6, c = idx & 63;
    float acc = b[c];
    #pragma unroll
    for (int k = 0; k < 3; ++k) acc = fmaf(x[n * 3 + k], W[k * H + c], acc);
    A[idx] = acc;
}

// ---------------- pre-norm: A = relu(LN(B, ln_g[layer], ln_b[layer])) ----------------
__global__ __launch_bounds__(256) void prenorm_k(const float* __restrict__ B,
                                                 const float* __restrict__ ln_g,
                                                 const float* __restrict__ ln_b,
                                                 float* __restrict__ A, int layer, int Nn) {
    int wid = threadIdx.x >> 6, lane = threadIdx.x & 63;
    int n = blockIdx.x * 4 + wid;
    if (n >= Nn) return;
    float v = B[n * H + lane];
    float mean = wave_sum(v) * (1.f / H);
    float dv = v - mean;
    float var = wave_sum(dv * dv) * (1.f / H);
    float inv = rsqrtf(var + LN_EPS);
    float z = fmaf(dv * inv, ln_g[layer * H + lane], ln_b[layer * H + lane]);
    A[n * H + lane] = fmaxf(z, 0.f);
}

// ---------------- conv: B = (resid? B : 0) + MLP(agg + A) ----------------
__global__ __launch_bounds__(256) void conv_k(
    const float* __restrict__ Ain, float* __restrict__ B,
    const int* __restrict__ row_start, const int* __restrict__ srcs,
    const float* __restrict__ t,
    const float* __restrict__ W1, const float* __restrict__ b1,
    const float* __restrict__ g, const float* __restrict__ beta,
    const float* __restrict__ W2, const float* __restrict__ b2,
    int layer, int resid, int Nn)
{
    __shared__ float lds_out[4][H];
    __shared__ float lds_y1[4][H2];
    int wid = threadIdx.x >> 6, lane = threadIdx.x & 63;
    int n = blockIdx.x * 4 + wid;
    bool valid = (n < Nn);
    int nc = valid ? n : 0;

    W1 += layer * H * H2; b1 += layer * H2; g += layer * H2; beta += layer * H2;
    W2 += layer * H2 * H; b2 += layer * H;
    float tval = t[layer];

    int beg = valid ? row_start[nc] : 0;
    int end = valid ? row_start[nc + 1] : 0;

    // online softmax aggregation, per-lane (= per-channel)
    float m = -INFINITY, dsum = 0.f, ssum = 0.f;
    for (int e = beg; e < end; ++e) {
        int si = srcs[e];
        float xv = Ain[si * H + lane];
        float msg = fmaxf(xv, 0.f) + EPS_MSG;
        float l = msg * tval;
        float nm = fmaxf(m, l);
        float e1 = __expf(m - nm);   // exp(-inf)=0 on first edge
        float e2 = __expf(l - nm);
        dsum = fmaf(dsum, e1, e2);
        ssum = fmaf(ssum, e1, msg * e2);
        m = nm;
    }
    float xn = Ain[nc * H + lane];
    float agg = (end > beg) ? (ssum / dsum) : 0.f;
    float outv = agg + xn;

    lds_out[wid][lane] = outv;
    __syncthreads();

    // y1 = out @ W1 + b1   (each lane: columns lane and lane+64)
    float y1a = b1[lane], y1b = b1[H + lane];
    #pragma unroll 8
    for (int c = 0; c < H; ++c) {
        float oc = lds_out[wid][c];
        y1a = fmaf(oc, W1[c * H2 + lane], y1a);
        y1b = fmaf(oc, W1[c * H2 + H + lane], y1b);
    }
    // LN over 128 (two-pass), * g + beta, relu
    float mean = wave_sum(y1a + y1b) * (1.f / H2);
    float da = y1a - mean, db = y1b - mean;
    float var = wave_sum(da * da + db * db) * (1.f / H2);
    float inv = rsqrtf(var + LN_EPS);
    float na = fmaxf(fmaf(da * inv, g[lane], beta[lane]), 0.f);
    float nb_ = fmaxf(fmaf(db * inv, g[H + lane], beta[H + lane]), 0.f);

    lds_y1[wid][lane] = na;
    lds_y1[wid][H + lane] = nb_;
    __syncthreads();

    // y2 = y1n @ W2 + b2
    float y2 = b2[lane];
    #pragma unroll 8
    for (int j = 0; j < H2; ++j)
        y2 = fmaf(lds_y1[wid][j], W2[j * H + lane], y2);

    if (valid) {
        float hv = resid ? (B[n * H + lane] + y2) : y2;
        B[n * H + lane] = hv;
    }
}

// ---------------- final: out = relu(LN(B, ln_g[0], ln_b[0])) @ lin_W + lin_b ----------------
__global__ __launch_bounds__(256) void final_k(const float* __restrict__ B,
                                               const float* __restrict__ ln_g,
                                               const float* __restrict__ ln_b,
                                               const float* __restrict__ lin_W,
                                               const float* __restrict__ lin_b,
                                               float* __restrict__ out, int Nn) {
    int wid = threadIdx.x >> 6, lane = threadIdx.x & 63;
    int n = blockIdx.x * 4 + wid;
    if (n >= Nn) return;
    float v = B[n * H + lane];
    float mean = wave_sum(v) * (1.f / H);
    float dv = v - mean;
    float var = wave_sum(dv * dv) * (1.f / H);
    float inv = rsqrtf(var + LN_EPS);
    float z = fmaxf(fmaf(dv * inv, ln_g[lane], ln_b[lane]), 0.f);
    float p0 = wave_sum(z * lin_W[lane * 3 + 0]);
    float p1 = wave_sum(z * lin_W[lane * 3 + 1]);
    float p2 = wave_sum(z * lin_W[lane * 3 + 2]);
    if (lane == 0) {
        out[n * 3 + 0] = p0 + lin_b[0];
        out[n * 3 + 1] = p1 + lin_b[1];
        out[n * 3 + 2] = p2 + lin_b[2];
    }
}

extern "C" void kernel_launch(void* const* d_in, const int* in_sizes, int n_in,
                              void* d_out, int out_size, void* d_ws, size_t ws_size,
                              hipStream_t stream) {
    const float* x        = (const float*)d_in[0];
    const int*   eidx     = (const int*)  d_in[1];
    const float* enc_W    = (const float*)d_in[2];
    const float* enc_b    = (const float*)d_in[3];
    const float* t        = (const float*)d_in[4];
    const float* mlp_W1   = (const float*)d_in[5];
    const float* mlp_b1   = (const float*)d_in[6];
    const float* mlp_g    = (const float*)d_in[7];
    const float* mlp_beta = (const float*)d_in[8];
    const float* mlp_W2   = (const float*)d_in[9];
    const float* mlp_b2   = (const float*)d_in[10];
    const float* ln_g     = (const float*)d_in[11];
    const float* ln_b     = (const float*)d_in[12];
    const float* lin_W    = (const float*)d_in[13];
    const float* lin_b    = (const float*)d_in[14];
    float* out = (float*)d_out;

    const int N = in_sizes[0] / 3;
    const int E = in_sizes[1] / 2;
    const int* src = eidx;
    const int* dst = eidx + E;

    // workspace layout
    float* A = (float*)d_ws;                    // N*64 f32
    float* Bm = A + (size_t)N * H;              // N*64 f32
    int* counts    = (int*)(Bm + (size_t)N * H);// N
    int* row_start = counts + N;                // N+1
    int* cursor    = row_start + N + 1;         // N
    int* partial   = cursor + N;                // N
    int* blockSums = partial + N;               // 512
    int* srcs_sorted = blockSums + 512;         // E

    const int nScanBlocks = (N + 255) / 256;

    hipMemsetAsync(counts, 0, (size_t)N * sizeof(int), stream);
    hist_k<<<(E + 255) / 256, 256, 0, stream>>>(dst, counts, E);
    scan_block_k<<<nScanBlocks, 256, 0, stream>>>(counts, partial, blockSums, N);
    scan_sums_k<<<1, 512, 0, stream>>>(blockSums, nScanBlocks);
    finalize_k<<<(N + 255) / 256, 256, 0, stream>>>(partial, blockSums, counts, row_start, cursor, N);
    scatter_k<<<(E + 255) / 256, 256, 0, stream>>>(src, dst, cursor, srcs_sorted, E);

    encoder_k<<<((size_t)N * H + 255) / 256, 256, 0, stream>>>(x, enc_W, enc_b, A, N);

    const int nodeBlocks = (N + 3) / 4;
    // layer 0: h = conv(h)  (input A, write B, no outer residual)
    conv_k<<<nodeBlocks, 256, 0, stream>>>(A, Bm, row_start, srcs_sorted, t,
                                           mlp_W1, mlp_b1, mlp_g, mlp_beta, mlp_W2, mlp_b2,
                                           0, 0, N);
    // layers 1..2: z = relu(LN(h)); h = h + conv(z)
    for (int layer = 1; layer < 3; ++layer) {
        prenorm_k<<<nodeBlocks, 256, 0, stream>>>(Bm, ln_g, ln_b, A, layer, N);
        conv_k<<<nodeBlocks, 256, 0, stream>>>(A, Bm, row_start, srcs_sorted, t,
                                               mlp_W1, mlp_b1, mlp_g, mlp_beta, mlp_W2, mlp_b2,
                                               layer, 1, N);
    }
    final_k<<<nodeBlocks, 256, 0, stream>>>(Bm, ln_g, ln_b, lin_W, lin_b, out, N);
}

// Round 2
// 1072.840 us; speedup vs baseline: 1.0568x; 1.0568x over previous
//
#include <hip/hip_runtime.h>
#include <hip/hip_bf16.h>
#include <math.h>

#define H 64
#define H2 128
#define NB 8            // nodes per wave
#define EPS_MSG 1e-7f
#define LN_EPS 1e-5f

__device__ __forceinline__ float wave_sum(float v) {
    #pragma unroll
    for (int o = 32; o > 0; o >>= 1) v += __shfl_xor(v, o, 64);
    return v;
}

// ---------------- CSR build ----------------
__global__ void hist_k(const int* __restrict__ dst, int* __restrict__ counts, int E) {
    int e = blockIdx.x * blockDim.x + threadIdx.x;
    if (e < E) atomicAdd(&counts[dst[e]], 1);
}

__global__ void scan_block_k(const int* __restrict__ counts, int* __restrict__ partial,
                             int* __restrict__ blockSums, int n) {
    __shared__ int tmp[256];
    int tid = threadIdx.x;
    int i = blockIdx.x * 256 + tid;
    tmp[tid] = (i < n) ? counts[i] : 0;
    __syncthreads();
    #pragma unroll
    for (int off = 1; off < 256; off <<= 1) {
        int t = (tid >= off) ? tmp[tid - off] : 0;
        __syncthreads();
        tmp[tid] += t;
        __syncthreads();
    }
    if (i < n) partial[i] = tmp[tid];
    if (tid == 255) blockSums[blockIdx.x] = tmp[255];
}

__global__ void scan_sums_k(int* __restrict__ blockSums, int nb) {
    __shared__ int tmp[512];
    int tid = threadIdx.x;
    tmp[tid] = (tid < nb) ? blockSums[tid] : 0;
    __syncthreads();
    #pragma unroll
    for (int off = 1; off < 512; off <<= 1) {
        int t = (tid >= off) ? tmp[tid - off] : 0;
        __syncthreads();
        tmp[tid] += t;
        __syncthreads();
    }
    if (tid < nb) blockSums[tid] = (tid == 0) ? 0 : tmp[tid - 1];  // exclusive
}

__global__ void finalize_k(const int* __restrict__ partial, const int* __restrict__ blockSums,
                           const int* __restrict__ counts, int* __restrict__ row_start,
                           int* __restrict__ cursor, int n) {
    int i = blockIdx.x * blockDim.x + threadIdx.x;
    if (i < n) {
        int rs = partial[i] + blockSums[i >> 8];   // inclusive prefix
        row_start[i + 1] = rs;
        cursor[i] = rs - counts[i];                // exclusive prefix
        if (i == 0) row_start[0] = 0;
    }
}

__global__ void scatter_k(const int* __restrict__ src, const int* __restrict__ dst,
                          int* __restrict__ cursor, int* __restrict__ srcs_sorted, int E) {
    int e = blockIdx.x * blockDim.x + threadIdx.x;
    if (e < E) {
        int d = dst[e];
        int pos = atomicAdd(&cursor[d], 1);
        srcs_sorted[pos] = src[e];
    }
}

// ---------------- encoder: A = x @ enc_W + enc_b ----------------
__global__ void encoder_k(const float* __restrict__ x, const float* __restrict__ W,
                          const float* __restrict__ b, float* __restrict__ A, int Nn) {
    int idx = blockIdx.x * blockDim.x + threadIdx.x;
    if (idx >= Nn * H) return;
    int n = idx >> 6, c = idx & 63;
    float acc = b[c];
    #pragma unroll
    for (int k = 0; k < 3; ++k) acc = fmaf(x[n * 3 + k], W[k * H + c], acc);
    A[idx] = acc;
}

// ---------------- pre-norm: A = relu(LN(B, ln_g[layer], ln_b[layer])) ----------------
__global__ __launch_bounds__(256) void prenorm_k(const float* __restrict__ B,
                                                 const float* __restrict__ ln_g,
                                                 const float* __restrict__ ln_b,
                                                 float* __restrict__ A, int layer, int Nn) {
    int wid = threadIdx.x >> 6, lane = threadIdx.x & 63;
    int n = blockIdx.x * 4 + wid;
    if (n >= Nn) return;
    float v = B[n * H + lane];
    float mean = wave_sum(v) * (1.f / H);
    float dv = v - mean;
    float var = wave_sum(dv * dv) * (1.f / H);
    float inv = rsqrtf(var + LN_EPS);
    float z = fmaf(dv * inv, ln_g[layer * H + lane], ln_b[layer * H + lane]);
    A[n * H + lane] = fmaxf(z, 0.f);
}

// ---------------- conv: B = (resid? B : 0) + MLP(agg + A), 8 nodes per wave ----------------
__global__ __launch_bounds__(256) void conv_k(
    const float* __restrict__ Ain, float* __restrict__ B,
    const int* __restrict__ row_start, const int* __restrict__ srcs,
    const float* __restrict__ t,
    const float* __restrict__ W1, const float* __restrict__ b1,
    const float* __restrict__ g, const float* __restrict__ beta,
    const float* __restrict__ W2, const float* __restrict__ b2,
    int layer, int resid, int Nn)
{
    // per-wave transposed activation tiles (read as same-address broadcasts)
    __shared__ float out_t[4][H][NB];    // [wave][c][node]   8 KB
    __shared__ float y1_t[4][H2][NB];    // [wave][j][node]  16 KB
    int wid = threadIdx.x >> 6, lane = threadIdx.x & 63;
    int n0 = (blockIdx.x * 4 + wid) * NB;

    W1 += layer * H * H2; b1 += layer * H2; g += layer * H2; beta += layer * H2;
    W2 += layer * H2 * H; b2 += layer * H;
    float tval = t[0];  // overwritten below; avoid unused warning
    tval = t[layer];

    // ---- phase 1: gather + online-softmax aggregation, one node at a time ----
    #pragma unroll 1
    for (int nb = 0; nb < NB; ++nb) {
        int n = n0 + nb;
        float outv = 0.f;
        if (n < Nn) {
            int beg = row_start[n], end = row_start[n + 1];
            float m = -INFINITY, dsum = 0.f, ssum = 0.f;
            // 1-deep software pipeline on the gathered row
            float xv = (beg < end) ? Ain[(size_t)srcs[beg] * H + lane] : 0.f;
            for (int e = beg; e < end; ++e) {
                float xv_next = (e + 1 < end) ? Ain[(size_t)srcs[e + 1] * H + lane] : 0.f;
                float msg = fmaxf(xv, 0.f) + EPS_MSG;
                float l = msg * tval;
                float nm = fmaxf(m, l);
                float sc = __expf(m - nm);   // exp(-inf)=0 on first edge
                float w  = __expf(l - nm);
                dsum = fmaf(dsum, sc, w);
                ssum = fmaf(ssum, sc, msg * w);
                m = nm;
                xv = xv_next;
            }
            float xn = Ain[(size_t)n * H + lane];
            float agg = (end > beg) ? (ssum / dsum) : 0.f;
            outv = agg + xn;
        }
        out_t[wid][lane][nb] = outv;   // transposed store (intra-wave only)
    }

    // ---- phase 2: y1 = out @ W1 + b1 ; LN(128) ; relu ----
    float a[NB], bb[NB];
    {
        float b1a = b1[lane], b1b = b1[H + lane];
        #pragma unroll
        for (int nb = 0; nb < NB; ++nb) { a[nb] = b1a; bb[nb] = b1b; }
    }
    #pragma unroll 4
    for (int c = 0; c < H; ++c) {
        float w1a = W1[c * H2 + lane];
        float w1b = W1[c * H2 + H + lane];
        float4 o0 = *(const float4*)&out_t[wid][c][0];
        float4 o1 = *(const float4*)&out_t[wid][c][4];
        a[0] = fmaf(o0.x, w1a, a[0]);  bb[0] = fmaf(o0.x, w1b, bb[0]);
        a[1] = fmaf(o0.y, w1a, a[1]);  bb[1] = fmaf(o0.y, w1b, bb[1]);
        a[2] = fmaf(o0.z, w1a, a[2]);  bb[2] = fmaf(o0.z, w1b, bb[2]);
        a[3] = fmaf(o0.w, w1a, a[3]);  bb[3] = fmaf(o0.w, w1b, bb[3]);
        a[4] = fmaf(o1.x, w1a, a[4]);  bb[4] = fmaf(o1.x, w1b, bb[4]);
        a[5] = fmaf(o1.y, w1a, a[5]);  bb[5] = fmaf(o1.y, w1b, bb[5]);
        a[6] = fmaf(o1.z, w1a, a[6]);  bb[6] = fmaf(o1.z, w1b, bb[6]);
        a[7] = fmaf(o1.w, w1a, a[7]);  bb[7] = fmaf(o1.w, w1b, bb[7]);
    }
    {
        float ga = g[lane], gb = g[H + lane];
        float bea = beta[lane], beb = beta[H + lane];
        #pragma unroll
        for (int nb = 0; nb < NB; ++nb) {
            float mean = wave_sum(a[nb] + bb[nb]) * (1.f / H2);
            float da = a[nb] - mean, db = bb[nb] - mean;
            float var = wave_sum(da * da + db * db) * (1.f / H2);
            float inv = rsqrtf(var + LN_EPS);
            float na  = fmaxf(fmaf(da * inv, ga, bea), 0.f);
            float nb_ = fmaxf(fmaf(db * inv, gb, beb), 0.f);
            y1_t[wid][lane][nb] = na;
            y1_t[wid][H + lane][nb] = nb_;
        }
    }

    // ---- phase 3: y2 = y1n @ W2 + b2 ----
    float y2[NB];
    {
        float b2v = b2[lane];
        #pragma unroll
        for (int nb = 0; nb < NB; ++nb) y2[nb] = b2v;
    }
    #pragma unroll 4
    for (int j = 0; j < H2; ++j) {
        float w2 = W2[j * H + lane];
        float4 y0 = *(const float4*)&y1_t[wid][j][0];
        float4 y1v = *(const float4*)&y1_t[wid][j][4];
        y2[0] = fmaf(y0.x, w2, y2[0]);
        y2[1] = fmaf(y0.y, w2, y2[1]);
        y2[2] = fmaf(y0.z, w2, y2[2]);
        y2[3] = fmaf(y0.w, w2, y2[3]);
        y2[4] = fmaf(y1v.x, w2, y2[4]);
        y2[5] = fmaf(y1v.y, w2, y2[5]);
        y2[6] = fmaf(y1v.z, w2, y2[6]);
        y2[7] = fmaf(y1v.w, w2, y2[7]);
    }
    #pragma unroll
    for (int nb = 0; nb < NB; ++nb) {
        int n = n0 + nb;
        if (n < Nn) {
            float hv = resid ? (B[(size_t)n * H + lane] + y2[nb]) : y2[nb];
            B[(size_t)n * H + lane] = hv;
        }
    }
}

// ---------------- final: out = relu(LN(B, ln_g[0], ln_b[0])) @ lin_W + lin_b ----------------
__global__ __launch_bounds__(256) void final_k(const float* __restrict__ B,
                                               const float* __restrict__ ln_g,
                                               const float* __restrict__ ln_b,
                                               const float* __restrict__ lin_W,
                                               const float* __restrict__ lin_b,
                                               float* __restrict__ out, int Nn) {
    int wid = threadIdx.x >> 6, lane = threadIdx.x & 63;
    int n = blockIdx.x * 4 + wid;
    if (n >= Nn) return;
    float v = B[n * H + lane];
    float mean = wave_sum(v) * (1.f / H);
    float dv = v - mean;
    float var = wave_sum(dv * dv) * (1.f / H);
    float inv = rsqrtf(var + LN_EPS);
    float z = fmaxf(fmaf(dv * inv, ln_g[lane], ln_b[lane]), 0.f);
    float p0 = wave_sum(z * lin_W[lane * 3 + 0]);
    float p1 = wave_sum(z * lin_W[lane * 3 + 1]);
    float p2 = wave_sum(z * lin_W[lane * 3 + 2]);
    if (lane == 0) {
        out[n * 3 + 0] = p0 + lin_b[0];
        out[n * 3 + 1] = p1 + lin_b[1];
        out[n * 3 + 2] = p2 + lin_b[2];
    }
}

extern "C" void kernel_launch(void* const* d_in, const int* in_sizes, int n_in,
                              void* d_out, int out_size, void* d_ws, size_t ws_size,
                              hipStream_t stream) {
    const float* x        = (const float*)d_in[0];
    const int*   eidx     = (const int*)  d_in[1];
    const float* enc_W    = (const float*)d_in[2];
    const float* enc_b    = (const float*)d_in[3];
    const float* t        = (const float*)d_in[4];
    const float* mlp_W1   = (const float*)d_in[5];
    const float* mlp_b1   = (const float*)d_in[6];
    const float* mlp_g    = (const float*)d_in[7];
    const float* mlp_beta = (const float*)d_in[8];
    const float* mlp_W2   = (const float*)d_in[9];
    const float* mlp_b2   = (const float*)d_in[10];
    const float* ln_g     = (const float*)d_in[11];
    const float* ln_b     = (const float*)d_in[12];
    const float* lin_W    = (const float*)d_in[13];
    const float* lin_b    = (const float*)d_in[14];
    float* out = (float*)d_out;

    const int N = in_sizes[0] / 3;
    const int E = in_sizes[1] / 2;
    const int* src = eidx;
    const int* dst = eidx + E;

    // workspace layout
    float* A = (float*)d_ws;                    // N*64 f32
    float* Bm = A + (size_t)N * H;              // N*64 f32
    int* counts    = (int*)(Bm + (size_t)N * H);// N
    int* row_start = counts + N;                // N+1
    int* cursor    = row_start + N + 1;         // N
    int* partial   = cursor + N;                // N
    int* blockSums = partial + N;               // 512
    int* srcs_sorted = blockSums + 512;         // E

    const int nScanBlocks = (N + 255) / 256;

    hipMemsetAsync(counts, 0, (size_t)N * sizeof(int), stream);
    hist_k<<<(E + 255) / 256, 256, 0, stream>>>(dst, counts, E);
    scan_block_k<<<nScanBlocks, 256, 0, stream>>>(counts, partial, blockSums, N);
    scan_sums_k<<<1, 512, 0, stream>>>(blockSums, nScanBlocks);
    finalize_k<<<(N + 255) / 256, 256, 0, stream>>>(partial, blockSums, counts, row_start, cursor, N);
    scatter_k<<<(E + 255) / 256, 256, 0, stream>>>(src, dst, cursor, srcs_sorted, E);

    encoder_k<<<((size_t)N * H + 255) / 256, 256, 0, stream>>>(x, enc_W, enc_b, A, N);

    const int nodeBlocks4  = (N + 3) / 4;                 // for prenorm/final (1 node/wave)
    const int convBlocks   = (N + 4 * NB - 1) / (4 * NB); // 8 nodes/wave
    // layer 0: h = conv(h)  (input A, write B, no outer residual)
    conv_k<<<convBlocks, 256, 0, stream>>>(A, Bm, row_start, srcs_sorted, t,
                                           mlp_W1, mlp_b1, mlp_g, mlp_beta, mlp_W2, mlp_b2,
                                           0, 0, N);
    // layers 1..2: z = relu(LN(h)); h = h + conv(z)
    for (int layer = 1; layer < 3; ++layer) {
        prenorm_k<<<nodeBlocks4, 256, 0, stream>>>(Bm, ln_g, ln_b, A, layer, N);
        conv_k<<<convBlocks, 256, 0, stream>>>(A, Bm, row_start, srcs_sorted, t,
                                               mlp_W1, mlp_b1, mlp_g, mlp_beta, mlp_W2, mlp_b2,
                                               layer, 1, N);
    }
    final_k<<<nodeBlocks4, 256, 0, stream>>>(Bm, ln_g, ln_b, lin_W, lin_b, out, N);
}